// Round 11
// baseline (44.230 us; speedup 1.0000x reference)
//
#include <hip/hip_runtime.h>
#include <stdint.h>

// Deformable 3x3 local correlation. Plane-linear LDS, global_load_lds
// staging, ds_read2-paired taps, mod-32 slot stride (r10 structure), now
// TY=2 / 512-thread blocks / 512 grid -> 2 blocks per CU: TLP hides the
// per-phase barrier + vmcnt-drain stalls that pinned occupancy at 39%.
// left/right (2,128,64,256) f32, extra_offset (2,18,64,256) f32,
// out (2,72,64,256) f32. GROUPS=8, cg=16, S=9.

#define NB 2
#define CC 128
#define HH 64
#define WW 256
#define GG 8
#define CG 16
#define SS 9
#define HW (HH * WW)
#define TY 2                     // output rows per block
#define RW 6                     // staged rows h0-RW .. h0+TY+RW-1 (14 interior)
#define NSLOT 16                 // 1 top guard + 14 data + 1 bottom guard
#define SLOTDW 288               // dwords per slot (multiple of 32; 16B-aligned)
#define B0 4                     // data starts at dword 4 (x=-1 -> dword 3)
#define BUFDW (NSLOT * SLOTDW)   // 4608 dw = 18.4 KB per buffer

typedef __attribute__((address_space(3))) uint32_t lds_t;
typedef const __attribute__((address_space(1))) uint32_t glb_t;

// stage one channel plane's window into buffer at BOFS_DW (dwords).
// 8 waves, <=14 rows: wave wv stages rows wv and wv+8 (64 lanes x 16B = row).
#define STAGE(BOFS_DW, RPCH)                                                   \
  _Pragma("unroll")                                                            \
  for (int rep = 0; rep < 2; ++rep) {                                          \
    const int r = wv + rep * 8;                                                \
    if (r < nrows) {                                                           \
      const float* src = (RPCH) + (row0 + r) * WW + (lane << 2);               \
      lds_t* dst = (lds_t*)&smem[(BOFS_DW) + (sbase + r) * SLOTDW + B0];       \
      __builtin_amdgcn_global_load_lds((glb_t*)src, dst, 16, 0, 0);            \
    }                                                                          \
  }

#define COMPUTE(BOFS, RPC)                                                     \
  if (__builtin_expect(badmask == 0, 1)) {                                     \
    _Pragma("unroll")                                                          \
    for (int s = 0; s < SS; ++s) {                                             \
      const float* p0 = (const float*)(sb + (BOFS) * 4 + lbase[s]);            \
      const float* p1 = p0 + SLOTDW;                                           \
      const float A = p0[0], B = p0[1];     /* ds_read2_b32 pair */            \
      const float C = p1[0], D = p1[1];     /* ds_read2_b32 pair */            \
      acc[s] += lv * (wA[s] * A + wB[s] * B + wC[s] * C + wD[s] * D);          \
    }                                                                          \
  } else {                                                                     \
    _Pragma("unroll")                                                          \
    for (int s = 0; s < SS; ++s) {                                             \
      const float x = (float)(s / 3 - 1) + eob[(2 * s) * HW] + (float)wcol;    \
      const float y = (float)(s % 3 - 1) + eob[(2 * s + 1) * HW] + (float)h;   \
      const float x0f = floorf(x), y0f = floorf(y);                            \
      const float fx0 = x - x0f, fx1 = 1.0f - fx0;                             \
      const float fy0 = y - y0f, fy1 = 1.0f - fy0;                             \
      const int x0 = (int)x0f, y0 = (int)y0f;                                  \
      const int x1 = x0 + 1,   y1 = y0 + 1;                                    \
      const bool vx0 = (unsigned)x0 < (unsigned)WW;                            \
      const bool vx1 = (unsigned)x1 < (unsigned)WW;                            \
      const bool vy0 = (unsigned)y0 < (unsigned)HH;                            \
      const bool vy1 = (unsigned)y1 < (unsigned)HH;                            \
      const float a = (vx0 && vy0) ? fx1 * fy1 : 0.0f;                         \
      const float b = (vx1 && vy0) ? fx0 * fy1 : 0.0f;                         \
      const float c2 = (vx0 && vy1) ? fx1 * fy0 : 0.0f;                        \
      const float d = (vx1 && vy1) ? fx0 * fy0 : 0.0f;                         \
      const int cx0 = min(max(x0, 0), WW - 1), cx1 = min(max(x1, 0), WW - 1);  \
      const int cy0 = min(max(y0, 0), HH - 1), cy1 = min(max(y1, 0), HH - 1);  \
      const float v = a * (RPC)[cy0 * WW + cx0] + b * (RPC)[cy0 * WW + cx1]    \
                    + c2 * (RPC)[cy1 * WW + cx0] + d * (RPC)[cy1 * WW + cx1];  \
      acc[s] += lv * v;                                                        \
    }                                                                          \
  }

__global__ __launch_bounds__(512) void corr_kernel(
    const float* __restrict__ left, const float* __restrict__ right,
    const float* __restrict__ eo, float* __restrict__ out)
{
    __shared__ float smem[2 * BUFDW];   // 36.9 KB -> two blocks co-resident

    const int tid = threadIdx.x;
    const int lane = tid & 63;
    const int wv = tid >> 6;                 // wave 0..7
    const int bid = blockIdx.x;
    const int g = bid & (GG - 1);
    const int h0 = ((bid >> 3) & 31) << 1;   // h-tile base (TY=2)
    const int n = bid >> 8;
    const int gch = g * CG;

    const int virt_row0 = h0 - RW;                        // slot 1 maps here
    const int row0 = max(0, virt_row0);
    const int row_last = min(HH - 1, h0 + TY + RW - 1);   // h0+7 interior
    const int nrows = row_last - row0 + 1;                // <= 14
    const int sbase = row0 - virt_row0 + 1;

    const int hh = tid >> 8;                 // 0..1 (wave-uniform)
    const int h = h0 + hh;
    const int wcol = tid & 255;
    const int pix = h * WW + wcol;

    const float* rnb = right + (size_t)n * CC * HW;
    const float* lp  = left  + (size_t)(n * CC + gch) * HW + pix;
    const float* eob = eo + (size_t)n * SS * 2 * HW + pix;
    const char* sb = (const char*)smem;

    int lbase[SS];
    float wA[SS], wB[SS], wC[SS], wD[SS];
    int badmask = 0;

#pragma unroll
    for (int s = 0; s < SS; ++s) {
        const float x = (float)(s / 3 - 1) + eob[(2 * s) * HW] + (float)wcol;
        const float y = (float)(s % 3 - 1) + eob[(2 * s + 1) * HW] + (float)h;
        const float x0f = floorf(x), y0f = floorf(y);
        const float fx0 = x - x0f, fx1 = 1.0f - fx0;
        const float fy0 = y - y0f, fy1 = 1.0f - fy0;
        const int x0 = (int)x0f, y0 = (int)y0f;
        const int x1 = x0 + 1,   y1 = y0 + 1;
        const bool vx0 = (unsigned)x0 < (unsigned)WW;
        const bool vx1 = (unsigned)x1 < (unsigned)WW;
        const bool vy0 = (unsigned)y0 < (unsigned)HH;
        const bool vy1 = (unsigned)y1 < (unsigned)HH;

        wA[s] = (vx0 && vy0) ? fx1 * fy1 : 0.0f;   // (x0,y0) -> p0[0]
        wB[s] = (vx1 && vy0) ? fx0 * fy1 : 0.0f;   // (x1,y0) -> p0[1]
        wC[s] = (vx0 && vy1) ? fx1 * fy0 : 0.0f;   // (x0,y1) -> p1[0]
        wD[s] = (vx1 && vy1) ? fx0 * fy0 : 0.0f;   // (x1,y1) -> p1[1]

        const int xc = min(max(x0, -1), WW);                       // [-1,256]
        const int rr = min(max(y0 - virt_row0 + 1, 0), NSLOT - 2); // [0,14]
        lbase[s] = (rr * SLOTDW + B0 + xc) * 4;

        if ((vy0 && (y0 < row0 || y0 > row_last)) ||
            (vy1 && (y1 < row0 || y1 > row_last)))
            badmask |= 1 << s;
    }

    float acc[SS];
#pragma unroll
    for (int s = 0; s < SS; ++s) acc[s] = 0.0f;

    const float* rp = rnb + (size_t)gch * HW;

    // zero both buffers (guard slots/cols must read 0.0)
    for (int i = tid; i < (2 * BUFDW) / 4; i += 512)
        *(float4*)&smem[4 * i] = make_float4(0.f, 0.f, 0.f, 0.f);
    __syncthreads();                 // zero visible before DMA writes

    STAGE(0, rp)                     // buf0 <- channel 0
    __syncthreads();                 // vmcnt drained: buf0 ready

    const float* rpc = rp;
    for (int c = 0; c < CG; c += 2, rpc += 2 * HW) {
        STAGE(BUFDW, rpc + HW)       // buf1 <- channel c+1 (async)
        {
            const float lv = lp[(size_t)c * HW];
            COMPUTE(0, rpc)
        }
        __syncthreads();             // buf1 ready; buf0 free
        if (c + 2 < CG) { STAGE(0, rpc + 2 * HW) }   // buf0 <- c+2 (async)
        {
            const float lv = lp[(size_t)(c + 1) * HW];
            COMPUTE(BUFDW, rpc + HW)
        }
        __syncthreads();             // buf0 ready; buf1 free
    }

    float* ob = out + ((size_t)(n * GG + g) * SS) * HW + pix;
#pragma unroll
    for (int s = 0; s < SS; ++s)
        ob[s * HW] = acc[s] * (1.0f / CG);
}

extern "C" void kernel_launch(void* const* d_in, const int* in_sizes, int n_in,
                              void* d_out, int out_size, void* d_ws, size_t ws_size,
                              hipStream_t stream) {
    const float* left  = (const float*)d_in[0];
    const float* right = (const float*)d_in[1];
    const float* eo    = (const float*)d_in[2];
    float* out = (float*)d_out;
    (void)d_ws; (void)ws_size; (void)in_sizes; (void)n_in; (void)out_size;

    dim3 grid(NB * (HH / TY) * GG);   // 512 blocks: (n, h-tile, group)
    dim3 block(512);                   // 8 waves; thread = (hh, w)
    corr_kernel<<<grid, block, 0, stream>>>(left, right, eo, out);
}

// Round 13
// 38.078 us; speedup vs baseline: 1.1616x; 1.1616x over previous
//
#include <hip/hip_runtime.h>
#include <stdint.h>

// Deformable 3x3 local correlation. Plane-linear LDS, global_load_lds
// staging, ds_read2-paired taps, mod-32 slot stride (r10 structure), now
// 4 channel planes per buffer (147.5KB LDS, 2x4 planes): barriers 17 -> 5.
// 1 block/CU; VGPR must stay ~64 (no per-thread staging arrays).
// left/right (2,128,64,256) f32, extra_offset (2,18,64,256) f32,
// out (2,72,64,256) f32. GROUPS=8, cg=16, S=9.

#define NB 2
#define CC 128
#define HH 64
#define WW 256
#define GG 8
#define CG 16
#define SS 9
#define HW (HH * WW)
#define TY 4                      // output rows per block
#define RW 5                      // staged rows h0-RW .. h0+TY+RW-1 (14 interior)
#define NSLOT 16                  // 1 top guard + 14 data + 1 bottom guard
#define SLOTDW 288                // dwords per slot (mult of 32; 16B-aligned)
#define B0 4                      // data starts at dword 4 (x=-1 -> dword 3)
#define PLANEDW (NSLOT * SLOTDW)  // 4608 dw per channel plane
#define NPLANE 8                  // 2 buffers x 4 planes
#define SMEMDW (NPLANE * PLANEDW) // 36864 dw = 147.5 KB

typedef __attribute__((address_space(3))) uint32_t lds_t;
typedef const __attribute__((address_space(1))) uint32_t glb_t;

// stage 4 channel planes (CH0..CH0+3) into planes at PB (dword offset).
// plane p staged by waves 0..nrows-1 (16 waves >= 14 rows): 64 lanes x 16B.
#define STAGE4(PB, CH0)                                                        \
  _Pragma("unroll")                                                            \
  for (int p = 0; p < 4; ++p) {                                                \
    if (wv < nrows) {                                                          \
      const float* src = rnb + (size_t)(gch + (CH0) + p) * HW                  \
                       + (row0 + wv) * WW + (lane << 2);                       \
      lds_t* dst = (lds_t*)&smem[(PB) + p * PLANEDW                            \
                                 + (sbase + wv) * SLOTDW + B0];                \
      __builtin_amdgcn_global_load_lds((glb_t*)src, dst, 16, 0, 0);            \
    }                                                                          \
  }

// compute 4 channels (CH0..CH0+3) from planes at PB.
#define COMPUTE4(PB, CH0)                                                      \
  _Pragma("unroll")                                                            \
  for (int c2 = 0; c2 < 4; ++c2) {                                             \
    const float lv = lp[(size_t)((CH0) + c2) * HW];                            \
    if (__builtin_expect(badmask == 0, 1)) {                                   \
      _Pragma("unroll")                                                        \
      for (int s = 0; s < SS; ++s) {                                           \
        const float* p0 =                                                      \
            (const float*)(sb + ((PB) + c2 * PLANEDW) * 4 + lbase[s]);         \
        const float* p1 = p0 + SLOTDW;                                         \
        const float A = p0[0], B = p0[1];   /* ds_read2_b32 pair */            \
        const float C = p1[0], D = p1[1];   /* ds_read2_b32 pair */            \
        acc[s] += lv * (wA[s] * A + wB[s] * B + wC[s] * C + wD[s] * D);        \
      }                                                                        \
    } else {                                                                   \
      const float* rpc = rnb + (size_t)(gch + (CH0) + c2) * HW;                \
      _Pragma("unroll")                                                        \
      for (int s = 0; s < SS; ++s) {                                           \
        const float x = (float)(s / 3 - 1) + eob[(2 * s) * HW] + (float)wcol;  \
        const float y = (float)(s % 3 - 1) + eob[(2 * s + 1) * HW] + (float)h; \
        const float x0f = floorf(x), y0f = floorf(y);                          \
        const float fx0 = x - x0f, fx1 = 1.0f - fx0;                           \
        const float fy0 = y - y0f, fy1 = 1.0f - fy0;                           \
        const int x0 = (int)x0f, y0 = (int)y0f;                                \
        const int x1 = x0 + 1,   y1 = y0 + 1;                                  \
        const bool vx0 = (unsigned)x0 < (unsigned)WW;                          \
        const bool vx1 = (unsigned)x1 < (unsigned)WW;                          \
        const bool vy0 = (unsigned)y0 < (unsigned)HH;                          \
        const bool vy1 = (unsigned)y1 < (unsigned)HH;                          \
        const float a = (vx0 && vy0) ? fx1 * fy1 : 0.0f;                       \
        const float b = (vx1 && vy0) ? fx0 * fy1 : 0.0f;                       \
        const float c3 = (vx0 && vy1) ? fx1 * fy0 : 0.0f;                      \
        const float d = (vx1 && vy1) ? fx0 * fy0 : 0.0f;                       \
        const int cx0 = min(max(x0, 0), WW - 1), cx1 = min(max(x1, 0), WW - 1);\
        const int cy0 = min(max(y0, 0), HH - 1), cy1 = min(max(y1, 0), HH - 1);\
        const float v = a * rpc[cy0 * WW + cx0] + b * rpc[cy0 * WW + cx1]      \
                      + c3 * rpc[cy1 * WW + cx0] + d * rpc[cy1 * WW + cx1];    \
        acc[s] += lv * v;                                                      \
      }                                                                        \
    }                                                                          \
  }

__global__ __launch_bounds__(1024) void corr_kernel(
    const float* __restrict__ left, const float* __restrict__ right,
    const float* __restrict__ eo, float* __restrict__ out)
{
    __shared__ float smem[SMEMDW];   // 147.5 KB -> 1 block/CU

    const int tid = threadIdx.x;
    const int lane = tid & 63;
    const int wv = tid >> 6;                 // wave 0..15
    const int bid = blockIdx.x;
    const int g = bid & (GG - 1);
    const int h0 = ((bid >> 3) & 15) << 2;
    const int n = bid >> 7;
    const int gch = g * CG;

    const int virt_row0 = h0 - RW;                        // slot 1 maps here
    const int row0 = max(0, virt_row0);
    const int row_last = min(HH - 1, h0 + TY + RW - 1);   // h0+8 interior
    const int nrows = row_last - row0 + 1;                // <= 14
    const int sbase = row0 - virt_row0 + 1;

    const int hh = tid >> 8;                 // 0..3 (wave-uniform)
    const int h = h0 + hh;
    const int wcol = tid & 255;
    const int pix = h * WW + wcol;

    const float* rnb = right + (size_t)n * CC * HW;
    const float* lp  = left  + (size_t)(n * CC + gch) * HW + pix;
    const float* eob = eo + (size_t)n * SS * 2 * HW + pix;
    const char* sb = (const char*)smem;

    int lbase[SS];
    float wA[SS], wB[SS], wC[SS], wD[SS];
    int badmask = 0;

#pragma unroll
    for (int s = 0; s < SS; ++s) {
        const float x = (float)(s / 3 - 1) + eob[(2 * s) * HW] + (float)wcol;
        const float y = (float)(s % 3 - 1) + eob[(2 * s + 1) * HW] + (float)h;
        const float x0f = floorf(x), y0f = floorf(y);
        const float fx0 = x - x0f, fx1 = 1.0f - fx0;
        const float fy0 = y - y0f, fy1 = 1.0f - fy0;
        const int x0 = (int)x0f, y0 = (int)y0f;
        const int x1 = x0 + 1,   y1 = y0 + 1;
        const bool vx0 = (unsigned)x0 < (unsigned)WW;
        const bool vx1 = (unsigned)x1 < (unsigned)WW;
        const bool vy0 = (unsigned)y0 < (unsigned)HH;
        const bool vy1 = (unsigned)y1 < (unsigned)HH;

        wA[s] = (vx0 && vy0) ? fx1 * fy1 : 0.0f;   // (x0,y0) -> p0[0]
        wB[s] = (vx1 && vy0) ? fx0 * fy1 : 0.0f;   // (x1,y0) -> p0[1]
        wC[s] = (vx0 && vy1) ? fx1 * fy0 : 0.0f;   // (x0,y1) -> p1[0]
        wD[s] = (vx1 && vy1) ? fx0 * fy0 : 0.0f;   // (x1,y1) -> p1[1]

        const int xc = min(max(x0, -1), WW);                       // [-1,256]
        const int rr = min(max(y0 - virt_row0 + 1, 0), NSLOT - 2); // [0,14]
        lbase[s] = (rr * SLOTDW + B0 + xc) * 4;

        if ((vy0 && (y0 < row0 || y0 > row_last)) ||
            (vy1 && (y1 < row0 || y1 > row_last)))
            badmask |= 1 << s;
    }

    float acc[SS];
#pragma unroll
    for (int s = 0; s < SS; ++s) acc[s] = 0.0f;

    // zero all planes (guard slots/cols must read 0.0)
    for (int i = tid; i < SMEMDW / 4; i += 1024)
        *(float4*)&smem[4 * i] = make_float4(0.f, 0.f, 0.f, 0.f);
    __syncthreads();                    // zero visible before DMA writes

    STAGE4(0, 0)                        // bufA <- ch 0..3
    __syncthreads();                    // vmcnt drained: bufA ready

    STAGE4(4 * PLANEDW, 4)              // bufB <- ch 4..7 (async)
    COMPUTE4(0, 0)
    __syncthreads();                    // bufB ready; bufA free

    STAGE4(0, 8)                        // bufA <- ch 8..11 (async)
    COMPUTE4(4 * PLANEDW, 4)
    __syncthreads();                    // bufA ready; bufB free

    STAGE4(4 * PLANEDW, 12)             // bufB <- ch 12..15 (async)
    COMPUTE4(0, 8)
    __syncthreads();                    // bufB ready

    COMPUTE4(4 * PLANEDW, 12)

    float* ob = out + ((size_t)(n * GG + g) * SS) * HW + pix;
#pragma unroll
    for (int s = 0; s < SS; ++s)
        ob[s * HW] = acc[s] * (1.0f / CG);
}

extern "C" void kernel_launch(void* const* d_in, const int* in_sizes, int n_in,
                              void* d_out, int out_size, void* d_ws, size_t ws_size,
                              hipStream_t stream) {
    const float* left  = (const float*)d_in[0];
    const float* right = (const float*)d_in[1];
    const float* eo    = (const float*)d_in[2];
    float* out = (float*)d_out;
    (void)d_ws; (void)ws_size; (void)in_sizes; (void)n_in; (void)out_size;

    dim3 grid(NB * (HH / TY) * GG);   // 256 blocks: (n, h-tile, group)
    dim3 block(1024);                  // 16 waves; thread = (hh, w)
    corr_kernel<<<grid, block, 0, stream>>>(left, right, eo, out);
}

// Round 15
// 25.445 us; speedup vs baseline: 1.7382x; 1.4965x over previous
//
#include <hip/hip_runtime.h>
#include <stdint.h>

// Deformable 3x3 local correlation. f16 CHANNEL-PAIR packed LDS: dword at
// col x of pair-plane p = (f16 ch[2p][x], f16 ch[2p+1][x]). Each tap dword
// serves 2 channels -> DS gathers halve (288->144/thread), bank density
// halves. All 16 channels resident (8 pair-planes, 147.5KB) -> 2 barriers
// total, no double-buffer. fdot2 (v_dot2_f32_f16) accumulates in f32.
// Per-s setup recomputed in-loop to fit the hard 64-VGPR cap (r6-r13
// lesson: cap is not overridable; WRITE_SIZE >> 9.2MB = spill tripwire).
// h2v must be __fp16-based: cvt_pkrtz/fdot2 builtins use __fp16 vectors
// (r14 compile fix).
// left/right (2,128,64,256) f32, extra_offset (2,18,64,256) f32,
// out (2,72,64,256) f32. GROUPS=8, cg=16, S=9.

#define NB 2
#define CC 128
#define HH 64
#define WW 256
#define GG 8
#define CG 16
#define SS 9
#define HW (HH * WW)
#define TY 4                      // output rows per block
#define RW 5                      // staged rows h0-RW .. h0+TY+RW-1 (14 interior)
#define NSLOT 16                  // 1 top guard + 14 data + 1 bottom guard
#define SLOTDW 288                // dwords per slot (mult of 32; 16B-aligned)
#define B0 4                      // col x -> dword B0+x  (x=-1 -> dword 3)
#define PLANEDW (NSLOT * SLOTDW)  // 4608 dw per pair-plane
#define NPAIR 8                   // 8 channel pairs = whole group
#define SMEMDW (NPAIR * PLANEDW)  // 36864 dw = 147.5 KB -> 1 block/CU

typedef __fp16 h2v __attribute__((ext_vector_type(2)));

static __device__ __forceinline__ uint32_t pkrtz(float a, float b) {
    h2v v = __builtin_amdgcn_cvt_pkrtz(a, b);
    return __builtin_bit_cast(uint32_t, v);
}
static __device__ __forceinline__ h2v u2h(uint32_t u) {
    return __builtin_bit_cast(h2v, u);
}

#if __has_builtin(__builtin_amdgcn_fdot2)
#define FDOT2(A, B, C) __builtin_amdgcn_fdot2((A), (B), (C), false)
#else
#define FDOT2(A, B, C) fmaf((float)(A).x, (float)(B).x, \
                            fmaf((float)(A).y, (float)(B).y, (C)))
#endif

__global__ __launch_bounds__(1024) void corr_kernel(
    const float* __restrict__ left, const float* __restrict__ right,
    const float* __restrict__ eo, float* __restrict__ out)
{
    __shared__ uint32_t smem[SMEMDW];

    const int tid = threadIdx.x;
    const int lane = tid & 63;
    const int wv = tid >> 6;                 // wave 0..15
    const int bid = blockIdx.x;
    const int g = bid & (GG - 1);
    const int h0 = ((bid >> 3) & 15) << 2;
    const int n = bid >> 7;
    const int gch = g * CG;

    const int virt_row0 = h0 - RW;                        // slot 1 maps here
    const int row0 = max(0, virt_row0);
    const int row_last = min(HH - 1, h0 + TY + RW - 1);   // h0+8 interior
    const int nrows = row_last - row0 + 1;                // <= 14
    const int sbase = row0 - virt_row0 + 1;

    const int hh = tid >> 8;                 // 0..3 (wave-uniform)
    const int h = h0 + hh;
    const int wcol = tid & 255;
    const int pix = h * WW + wcol;

    const float* rnb = right + (size_t)n * CC * HW;
    const float* lp  = left  + (size_t)(n * CC + gch) * HW + pix;
    const float* eob = eo + (size_t)n * SS * 2 * HW + pix;

    // zero LDS: guard slots/cols must read as 0.0 (f16 zero == 0x0000)
    for (int i = tid; i < SMEMDW / 4; i += 1024)
        *(uint4*)&smem[4 * i] = make_uint4(0u, 0u, 0u, 0u);
    __syncthreads();

    // stage all 8 pair-planes: wave wv handles window row wv of each plane.
    // lane covers cols 4l..4l+3: 2x float4 load -> 4x cvt_pkrtz -> b128 write.
#pragma unroll
    for (int p = 0; p < NPAIR; ++p) {
        if (wv < nrows) {
            const float* s0 = rnb + (size_t)(gch + 2 * p) * HW
                            + (row0 + wv) * WW + 4 * lane;
            const float4 a = *(const float4*)s0;
            const float4 b = *(const float4*)(s0 + HW);
            uint4 o;
            o.x = pkrtz(a.x, b.x);
            o.y = pkrtz(a.y, b.y);
            o.z = pkrtz(a.z, b.z);
            o.w = pkrtz(a.w, b.w);
            *(uint4*)&smem[p * PLANEDW + (sbase + wv) * SLOTDW + B0 + 4 * lane] = o;
        }
    }

    // left values, packed per pair
    uint32_t lvpk[NPAIR];
#pragma unroll
    for (int p = 0; p < NPAIR; ++p)
        lvpk[p] = pkrtz(lp[(size_t)(2 * p) * HW], lp[(size_t)(2 * p + 1) * HW]);

    __syncthreads();                 // planes staged; no more barriers

    float acc[SS];
#pragma unroll
    for (int s = 0; s < SS; ++s) acc[s] = 0.0f;

    const char* sb = (const char*)smem;

#pragma unroll
    for (int s = 0; s < SS; ++s) {
        const float x = (float)(s / 3 - 1) + eob[(2 * s) * HW] + (float)wcol;
        const float y = (float)(s % 3 - 1) + eob[(2 * s + 1) * HW] + (float)h;
        const float x0f = floorf(x), y0f = floorf(y);
        const float fx0 = x - x0f, fx1 = 1.0f - fx0;
        const float fy0 = y - y0f, fy1 = 1.0f - fy0;
        const int x0 = (int)x0f, y0 = (int)y0f;
        const int x1 = x0 + 1,   y1 = y0 + 1;
        const bool vx0 = (unsigned)x0 < (unsigned)WW;
        const bool vx1 = (unsigned)x1 < (unsigned)WW;
        const bool vy0 = (unsigned)y0 < (unsigned)HH;
        const bool vy1 = (unsigned)y1 < (unsigned)HH;
        const float wA = (vx0 && vy0) ? fx1 * fy1 : 0.0f;   // (x0,y0)
        const float wB = (vx1 && vy0) ? fx0 * fy1 : 0.0f;   // (x1,y0)
        const float wC = (vx0 && vy1) ? fx1 * fy0 : 0.0f;   // (x0,y1)
        const float wD = (vx1 && vy1) ? fx0 * fy0 : 0.0f;   // (x1,y1)

        const bool bad = (vy0 && (y0 < row0 || y0 > row_last)) ||
                         (vy1 && (y1 < row0 || y1 > row_last));

        if (__builtin_expect(!bad, 1)) {
            const int xc = min(max(x0, -1), WW);                       // [-1,256]
            const int rr = min(max(y0 - virt_row0 + 1, 0), NSLOT - 2); // [0,14]
            const char* base = sb + (size_t)((rr * SLOTDW + B0 + xc) * 4);
#pragma unroll
            for (int p = 0; p < NPAIR; ++p) {
                const char* bp = base + p * (PLANEDW * 4);
                const h2v A  = *(const h2v*)(bp);                  // (x0,y0) 2ch
                const h2v Bv = *(const h2v*)(bp + 4);              // (x1,y0)
                const h2v Cv = *(const h2v*)(bp + SLOTDW * 4);     // (x0,y1)
                const h2v Dv = *(const h2v*)(bp + SLOTDW * 4 + 4); // (x1,y1)
                const h2v lv = u2h(lvpk[p]);
                float t =    wA * FDOT2(A,  lv, 0.0f);
                t = fmaf(wB, FDOT2(Bv, lv, 0.0f), t);
                t = fmaf(wC, FDOT2(Cv, lv, 0.0f), t);
                t = fmaf(wD, FDOT2(Dv, lv, 0.0f), t);
                acc[s] += t;
            }
        } else {
            // ~never (needs |eo| > ~4.5 sigma): full-precision global fallback
            const int cx0 = min(max(x0, 0), WW - 1), cx1 = min(max(x1, 0), WW - 1);
            const int cy0 = min(max(y0, 0), HH - 1), cy1 = min(max(y1, 0), HH - 1);
#pragma unroll
            for (int p = 0; p < NPAIR; ++p) {
                const h2v lv = u2h(lvpk[p]);
#pragma unroll
                for (int c2 = 0; c2 < 2; ++c2) {
                    const float* rp2 = rnb + (size_t)(gch + 2 * p + c2) * HW;
                    const float v = wA * rp2[cy0 * WW + cx0] + wB * rp2[cy0 * WW + cx1]
                                  + wC * rp2[cy1 * WW + cx0] + wD * rp2[cy1 * WW + cx1];
                    acc[s] += (c2 ? (float)lv.y : (float)lv.x) * v;
                }
            }
        }
    }

    float* ob = out + ((size_t)(n * GG + g) * SS) * HW + pix;
#pragma unroll
    for (int s = 0; s < SS; ++s)
        ob[s * HW] = acc[s] * (1.0f / CG);
}

extern "C" void kernel_launch(void* const* d_in, const int* in_sizes, int n_in,
                              void* d_out, int out_size, void* d_ws, size_t ws_size,
                              hipStream_t stream) {
    const float* left  = (const float*)d_in[0];
    const float* right = (const float*)d_in[1];
    const float* eo    = (const float*)d_in[2];
    float* out = (float*)d_out;
    (void)d_ws; (void)ws_size; (void)in_sizes; (void)n_in; (void)out_size;

    dim3 grid(NB * (HH / TY) * GG);   // 256 blocks: (n, h-tile, group)
    dim3 block(1024);                  // 16 waves; thread = (hh, w)
    corr_kernel<<<grid, block, 0, stream>>>(left, right, eo, out);
}